// Round 5
// baseline (693.926 us; speedup 1.0000x reference)
//
#include <hip/hip_runtime.h>

#define NROWS 50000
#define CDIM 8
#define XDIM 256
#define HDIM 256

typedef __attribute__((ext_vector_type(8))) short bf16x8;  // MFMA bf16 operand (4 VGPRs)
typedef __attribute__((ext_vector_type(4))) float f32x4;   // MFMA accumulator
typedef __attribute__((ext_vector_type(2))) float f32x2;

// fp32 -> bf16 round-to-nearest-even
__device__ __forceinline__ unsigned short f2bf_rne(float f) {
    unsigned int u = __builtin_bit_cast(unsigned int, f);
    u += 0x7fffu + ((u >> 16) & 1u);
    return (unsigned short)(u >> 16);
}
// two floats -> packed u32 of 2 bf16 (lo = low 16 bits)
__device__ __forceinline__ unsigned int pack2(float lo, float hi) {
    return (unsigned int)f2bf_rne(lo) | ((unsigned int)f2bf_rne(hi) << 16);
}

// Pack W_left / W_right / W_top into MFMA A-operand fragment layout in ws:
//   tile = ((seg*8 + xc)*16 + ht), 64 lanes x 16 B.
//   value[lane][j] = W_seg[ xc*32 + (lane>>4)*8 + j ][ ht*16 + (lane&15) ]
__global__ __launch_bounds__(256) void pack_weights(
        const float* __restrict__ Wl, const float* __restrict__ Wr,
        const float* __restrict__ Wt, bf16x8* __restrict__ wp) {
    int t = blockIdx.x * 256 + threadIdx.x;   // 24576 threads
    int lane = t & 63;
    int tile = t >> 6;          // 0..383
    int ht  = tile & 15;
    int sx  = tile >> 4;
    int xc  = sx & 7;
    int seg = sx >> 3;
    const float* __restrict__ W = (seg == 0) ? Wl : (seg == 1) ? Wr : Wt;
    int x0 = xc * 32 + (lane >> 4) * 8;
    int h  = ht * 16 + (lane & 15);
    bf16x8 frag;
#pragma unroll
    for (int j = 0; j < 8; ++j)
        frag[j] = (short)f2bf_rne(W[(size_t)(x0 + j) * HDIM + h]);
    wp[t] = frag;
}

// MEASUREMENT ROUND: exact round-4 kernel, body executed TWICE (idempotent;
// pass 2 recomputes and overwrites identical values). Doubled dispatch
// (~340-390 us) crosses the ~247 us top-5 cutoff so rocprof exposes this
// structure's own counters (FETCH/VALU/MFMA/conflicts). Memory clobber at
// rep top prevents cross-rep CSE (rule #17). Cross-rep LDS hand-off audited:
// chlds[0]'s last reader is xc=6 (two barriers before rep-2 prologue write).
__global__ __launch_bounds__(256, 3) void tbcnn_main(
        const float* __restrict__ child, const float* __restrict__ parent,
        const bf16x8* __restrict__ wp, const float* __restrict__ bias,
        float* __restrict__ out) {
    // [buf][c][rh][row8][slot][4 floats]: 32 KiB
    __shared__ __align__(16) float chlds[2][CDIM][2][8][8][4];
    __shared__ __align__(16) bf16x8 flds[2][3 * 64];   // 6 KiB: [buf][seg*64+lane]

    const int tid  = threadIdx.x;
    const int wave = tid >> 6;
    const int lane = tid & 63;
    const int r    = lane & 15;   // row_local (frag n / D col)
    const int p2   = lane >> 4;   // producer: x-pair sel; consumer: quad
    const int blk16 = blockIdx.x * 16;

    // staging-lane decomposition for global_load_lds
    const int row8 = lane >> 3;
    const int slot = lane & 7;
    const int gch  = slot ^ row8;         // swizzled source chunk

    const float lwt[8] = {7.f/7.f, 6.f/7.f, 5.f/7.f, 4.f/7.f, 3.f/7.f, 2.f/7.f, 1.f/7.f, 0.f/7.f};
    const float rwt[8] = {0.f/7.f, 1.f/7.f, 2.f/7.f, 3.f/7.f, 4.f/7.f, 5.f/7.f, 6.f/7.f, 7.f/7.f};

#pragma unroll 1
    for (int rep = 0; rep < 2; ++rep) {
        asm volatile("" ::: "memory");   // forbid merging/eliding the passes

        f32x4 acc[4];
#pragma unroll
        for (int t = 0; t < 4; ++t) acc[t] = (f32x4){0.f, 0.f, 0.f, 0.f};

        // ---- prologue: issue batch for xc=0 into buf 0 ----
        f32x2 pnxt;
        {
#pragma unroll
            for (int k = 0; k < 4; ++k) {
                const int i = k * 4 + wave;          // 4 instrs/wave, uniform
                const int c = i >> 1, rh = i & 1;
                const float* src = child + (size_t)(blk16 + rh * 8 + row8) * (CDIM * XDIM)
                                 + c * XDIM + 0 * 32 + gch * 4;
                __builtin_amdgcn_global_load_lds(
                    (const __attribute__((address_space(1))) unsigned int*)src,
                    (__attribute__((address_space(3))) unsigned int*)&chlds[0][c][rh][0][0][0],
                    16, 0, 0);
            }
            pnxt = *(const f32x2*)(parent + (size_t)(blk16 + r) * XDIM + 0 * 32 + wave * 8 + p2 * 2);
        }

#pragma unroll 1
        for (int xc = 0; xc < 8; ++xc) {
            const int cb = xc & 1;
            const f32x2 pcur = pnxt;

            if (xc < 7) {
                // issue batch xc+1 into chlds[cb^1] (its previous readers drained
                // at lgkmcnt(0)+barrier of iter xc-1)
#pragma unroll
                for (int k = 0; k < 4; ++k) {
                    const int i = k * 4 + wave;
                    const int c = i >> 1, rh = i & 1;
                    const float* src = child + (size_t)(blk16 + rh * 8 + row8) * (CDIM * XDIM)
                                     + c * XDIM + (xc + 1) * 32 + gch * 4;
                    __builtin_amdgcn_global_load_lds(
                        (const __attribute__((address_space(1))) unsigned int*)src,
                        (__attribute__((address_space(3))) unsigned int*)&chlds[cb ^ 1][c][rh][0][0][0],
                        16, 0, 0);
                }
                pnxt = *(const f32x2*)(parent + (size_t)(blk16 + r) * XDIM + (xc + 1) * 32 + wave * 8 + p2 * 2);
                // own outstanding: 5 new (4 gload_lds + parent). Oldest-first
                // drain completes batch xc while batch xc+1 flies.
                asm volatile("s_waitcnt vmcnt(5)" ::: "memory");
            } else {
                asm volatile("s_waitcnt vmcnt(0)" ::: "memory");
            }
            __builtin_amdgcn_s_barrier();          // Barrier1: chlds[cb] staged
            asm volatile("" ::: "memory");

            // ---- reduce: frags for this xc (wave w produces x-octet w) ----
            {
                const int rh_r = r >> 3, r8 = r & 7;
                const int sl_  = (wave * 2 + (p2 >> 1)) ^ r8;   // read-side swizzle
                const int sub  = (p2 & 1) * 2;
                float sl0 = 0.f, sl1 = 0.f, sr0 = 0.f, sr1 = 0.f;
#pragma unroll
                for (int c = 0; c < CDIM; ++c) {
                    f32x2 a = *(const f32x2*)&chlds[cb][c][rh_r][r8][sl_][sub];
                    sl0 += a[0] * lwt[c];  sl1 += a[1] * lwt[c];
                    sr0 += a[0] * rwt[c];  sr1 += a[1] * rwt[c];
                }
                ((unsigned int*)&flds[cb][0 * 64 + wave * 16 + r])[p2] = pack2(sl0, sl1);
                ((unsigned int*)&flds[cb][1 * 64 + wave * 16 + r])[p2] = pack2(sr0, sr1);
                ((unsigned int*)&flds[cb][2 * 64 + wave * 16 + r])[p2] = pack2(pcur[0], pcur[1]);
            }
            asm volatile("s_waitcnt lgkmcnt(0)" ::: "memory");  // frag writes + child reads done
            __builtin_amdgcn_s_barrier();          // Barrier2: frags visible
            asm volatile("" ::: "memory");

            // ---- MFMA: wave w consumes h-quadrant w (3 segs x 4 h-tiles) ----
#pragma unroll
            for (int seg = 0; seg < 3; ++seg) {
                const bf16x8* wb = wp + ((size_t)((seg * 8 + xc) * 16 + wave * 4)) * 64 + lane;
                bf16x8 f = flds[cb][seg * 64 + lane];
#pragma unroll
                for (int t = 0; t < 4; ++t)
                    acc[t] = __builtin_amdgcn_mfma_f32_16x16x32_bf16(wb[t * 64], f, acc[t], 0, 0, 0);
            }
        }

        // ---- epilogue: bias + relu; D col = r, D row = p2*4 + j ----
        float* __restrict__ orow = out + (size_t)(blk16 + r) * HDIM;
#pragma unroll
        for (int t = 0; t < 4; ++t) {
            const int h = (wave * 4 + t) * 16 + p2 * 4;
            f32x4 b4 = *(const f32x4*)(bias + h);
            f32x4 v = acc[t];
            v[0] = fmaxf(v[0] + b4[0], 0.f);
            v[1] = fmaxf(v[1] + b4[1], 0.f);
            v[2] = fmaxf(v[2] + b4[2], 0.f);
            v[3] = fmaxf(v[3] + b4[3], 0.f);
            *(f32x4*)(orow + h) = v;
        }
    }
}

// Correct-but-slow fallback if ws is too small for the packed weights.
__global__ __launch_bounds__(256) void tbcnn_fallback(
        const float* __restrict__ child, const float* __restrict__ parent,
        const float* __restrict__ Wl, const float* __restrict__ Wr,
        const float* __restrict__ Wt, const float* __restrict__ bias,
        float* __restrict__ out) {
    __shared__ float sl[XDIM], sr[XDIM], sp[XDIM];
    const int n = blockIdx.x;
    const int h = threadIdx.x;
    const float lwt[8] = {7.f/7.f, 6.f/7.f, 5.f/7.f, 4.f/7.f, 3.f/7.f, 2.f/7.f, 1.f/7.f, 0.f/7.f};
    const float rwt[8] = {0.f/7.f, 1.f/7.f, 2.f/7.f, 3.f/7.f, 4.f/7.f, 5.f/7.f, 6.f/7.f, 7.f/7.f};
    const float* ch = child + (size_t)n * (CDIM * XDIM);
    float al = 0.f, ar = 0.f;
#pragma unroll
    for (int c = 0; c < CDIM; ++c) {
        float v = ch[c * XDIM + h];
        al += lwt[c] * v;
        ar += rwt[c] * v;
    }
    sl[h] = al; sr[h] = ar; sp[h] = parent[(size_t)n * XDIM + h];
    __syncthreads();
    float a = bias[h];
    for (int x = 0; x < XDIM; ++x)
        a += sl[x] * Wl[(size_t)x * HDIM + h] + sr[x] * Wr[(size_t)x * HDIM + h]
           + sp[x] * Wt[(size_t)x * HDIM + h];
    out[(size_t)n * HDIM + h] = fmaxf(a, 0.f);
}

extern "C" void kernel_launch(void* const* d_in, const int* in_sizes, int n_in,
                              void* d_out, int out_size, void* d_ws, size_t ws_size,
                              hipStream_t stream) {
    const float* child  = (const float*)d_in[0];
    const float* parent = (const float*)d_in[1];
    const float* Wl     = (const float*)d_in[2];
    const float* Wr     = (const float*)d_in[3];
    const float* Wt     = (const float*)d_in[4];
    const float* bias   = (const float*)d_in[5];
    float* out = (float*)d_out;

    const size_t wp_bytes = (size_t)3 * XDIM * HDIM * sizeof(unsigned short); // 384 KiB
    if (ws_size >= wp_bytes) {
        bf16x8* wp = (bf16x8*)d_ws;
        pack_weights<<<96, 256, 0, stream>>>(Wl, Wr, Wt, wp);
        const int n_blocks = NROWS / 16;                 // 3125, exact
        tbcnn_main<<<n_blocks, 256, 0, stream>>>(child, parent, wp, bias, out);
    } else {
        tbcnn_fallback<<<NROWS, 256, 0, stream>>>(child, parent, Wl, Wr, Wt, bias, out);
    }
}

// Round 6
// 597.123 us; speedup vs baseline: 1.1621x; 1.1621x over previous
//
#include <hip/hip_runtime.h>

#define NROWS 50000
#define CDIM 8
#define XDIM 256
#define HDIM 256

typedef __attribute__((ext_vector_type(8))) short bf16x8;  // MFMA bf16 operand (4 VGPRs)
typedef __attribute__((ext_vector_type(4))) float f32x4;   // MFMA accumulator

// fp32 -> bf16 round-to-nearest-even
__device__ __forceinline__ unsigned short f2bf_rne(float f) {
    unsigned int u = __builtin_bit_cast(unsigned int, f);
    u += 0x7fffu + ((u >> 16) & 1u);
    return (unsigned short)(u >> 16);
}
// two floats -> packed u32 of 2 bf16 (lo = low 16 bits)
__device__ __forceinline__ unsigned int pack2(float lo, float hi) {
    return (unsigned int)f2bf_rne(lo) | ((unsigned int)f2bf_rne(hi) << 16);
}

// Pack W_left / W_right / W_top into MFMA A-operand fragment layout in ws:
//   tile = ((seg*8 + xc)*16 + ht), 64 lanes x 16 B.
//   value[lane][j] = W_seg[ xc*32 + (lane>>4)*8 + j ][ ht*16 + (lane&15) ]
__global__ __launch_bounds__(256) void pack_weights(
        const float* __restrict__ Wl, const float* __restrict__ Wr,
        const float* __restrict__ Wt, bf16x8* __restrict__ wp) {
    int t = blockIdx.x * 256 + threadIdx.x;   // 24576 threads
    int lane = t & 63;
    int tile = t >> 6;          // 0..383
    int ht  = tile & 15;
    int sx  = tile >> 4;
    int xc  = sx & 7;
    int seg = sx >> 3;
    const float* __restrict__ W = (seg == 0) ? Wl : (seg == 1) ? Wr : Wt;
    int x0 = xc * 32 + (lane >> 4) * 8;
    int h  = ht * 16 + (lane & 15);
    bf16x8 frag;
#pragma unroll
    for (int j = 0; j < 8; ++j)
        frag[j] = (short)f2bf_rne(W[(size_t)(x0 + j) * HDIM + h]);
    wp[t] = frag;
}

// ROUND 6: sequential-streaming Phase A. Evidence (round-5 double-pass):
// cold pass 176 us vs L3-warm pass 89 us with identical instructions ->
// the limit is DRAM access pattern (scattered 128-B granules at ~2.5 TB/s;
// the fill kernel does 6.5 TB/s sequential). Phase A reads child in fully
// contiguous 1-KB instructions, sequential within each 8-KB row and across
// the block's 128-KB slab. sl/sr reduced in registers (lane l owns x=4l..4l+3),
// packed to bf16, granule-swizzled into 24 KB LDS. ONE barrier total.
// Phase B = round-4's verified MFMA consumer (identical frag content:
// frag[lane][j] = s[r][xc*32 + quad*8 + j]; identical accumulation chain).
__global__ __launch_bounds__(256, 3) void tbcnn_main(
        const float* __restrict__ child, const float* __restrict__ parent,
        const bf16x8* __restrict__ wp, const float* __restrict__ bias,
        float* __restrict__ out) {
    // bf16 [arr][row][x], granule(16B)-swizzled: logical granule g of row rr
    // stored at physical granule g ^ (rr&7). 24 KiB.
    __shared__ __align__(16) short s_lds[3][16][256];

    const int tid  = threadIdx.x;
    const int wave = tid >> 6;
    const int lane = tid & 63;
    const int r    = lane & 15;   // consumer: row_local (frag n / D col)
    const int quad = lane >> 4;   // consumer: k-octet selector
    const int blk16 = blockIdx.x * 16;

    const float lwt[8] = {7.f/7.f, 6.f/7.f, 5.f/7.f, 4.f/7.f, 3.f/7.f, 2.f/7.f, 1.f/7.f, 0.f/7.f};
    const float rwt[8] = {0.f/7.f, 1.f/7.f, 2.f/7.f, 3.f/7.f, 4.f/7.f, 5.f/7.f, 6.f/7.f, 7.f/7.f};

    // ---- Phase A: contiguous streaming reduce (wave w owns rows 4w..4w+3) ----
#pragma unroll
    for (int i = 0; i < 4; ++i) {
        const int rr  = wave * 4 + i;
        const int row = blk16 + rr;
        const float* __restrict__ cr = child + (size_t)row * (CDIM * XDIM) + lane * 4;
        f32x4 sl = (f32x4){0.f, 0.f, 0.f, 0.f};
        f32x4 sr = (f32x4){0.f, 0.f, 0.f, 0.f};
#pragma unroll
        for (int c = 0; c < CDIM; ++c) {
            f32x4 v = *(const f32x4*)(cr + c * XDIM);   // 64 lanes x 16 B = 1 KB contiguous
            sl += v * lwt[c];
            sr += v * rwt[c];
        }
        f32x4 pv = *(const f32x4*)(parent + (size_t)row * XDIM + lane * 4);

        // lane l covers x = 4l..4l+3 = half of granule g = l>>1 (sub = l&1).
        // physical byte offset within row: (g ^ (rr&7))*16 + (l&1)*8.
        const int gp = (((lane >> 1) ^ (rr & 7)) << 4) + ((lane & 1) << 3);
        unsigned long long wsl = (unsigned long long)pack2(sl[0], sl[1])
                               | ((unsigned long long)pack2(sl[2], sl[3]) << 32);
        unsigned long long wsr = (unsigned long long)pack2(sr[0], sr[1])
                               | ((unsigned long long)pack2(sr[2], sr[3]) << 32);
        unsigned long long wpp = (unsigned long long)pack2(pv[0], pv[1])
                               | ((unsigned long long)pack2(pv[2], pv[3]) << 32);
        *(unsigned long long*)((char*)&s_lds[0][rr][0] + gp) = wsl;
        *(unsigned long long*)((char*)&s_lds[1][rr][0] + gp) = wsr;
        *(unsigned long long*)((char*)&s_lds[2][rr][0] + gp) = wpp;
    }
    __syncthreads();   // the only barrier

    // ---- Phase B: MFMA; wave w consumes h-quadrant w (3 segs x 4 h-tiles) ----
    f32x4 acc[4];
#pragma unroll
    for (int t = 0; t < 4; ++t) acc[t] = (f32x4){0.f, 0.f, 0.f, 0.f};

    // weight tile (seg, xc, t): wbase[seg*8192 + xc*1024 + t*64]
    const bf16x8* __restrict__ wbase = wp + (size_t)(wave * 256 + lane);
    bf16x8 wn[4];
#pragma unroll
    for (int t = 0; t < 4; ++t) wn[t] = wbase[t * 64];   // prefetch (seg0, xc0)

#pragma unroll 1
    for (int xc = 0; xc < 8; ++xc) {
        // frags: ds_read_b128 at swizzled granule (xc*4+quad) ^ (r&7)
        const int goff = (((xc * 4 + quad) ^ (r & 7)) << 4);
        bf16x8 fr[3];
#pragma unroll
        for (int a = 0; a < 3; ++a)
            fr[a] = *(const bf16x8*)((const char*)&s_lds[a][r][0] + goff);
#pragma unroll
        for (int seg = 0; seg < 3; ++seg) {
            bf16x8 wc[4];
#pragma unroll
            for (int t = 0; t < 4; ++t) wc[t] = wn[t];
            // prefetch next (seg+1, xc) or (0, xc+1); xc=7 tail wraps (discarded)
            const int noff = (seg < 2) ? ((seg + 1) * 8192 + xc * 1024)
                                       : (((xc + 1) & 7) * 1024);
#pragma unroll
            for (int t = 0; t < 4; ++t) wn[t] = wbase[noff + t * 64];
#pragma unroll
            for (int t = 0; t < 4; ++t)
                acc[t] = __builtin_amdgcn_mfma_f32_16x16x32_bf16(wc[t], fr[seg], acc[t], 0, 0, 0);
        }
    }

    // ---- epilogue: bias + relu; D col = r, D row = quad*4 + j ----
    float* __restrict__ orow = out + (size_t)(blk16 + r) * HDIM;
#pragma unroll
    for (int t = 0; t < 4; ++t) {
        const int h = (wave * 4 + t) * 16 + quad * 4;
        f32x4 b4 = *(const f32x4*)(bias + h);
        f32x4 v = acc[t];
        v[0] = fmaxf(v[0] + b4[0], 0.f);
        v[1] = fmaxf(v[1] + b4[1], 0.f);
        v[2] = fmaxf(v[2] + b4[2], 0.f);
        v[3] = fmaxf(v[3] + b4[3], 0.f);
        *(f32x4*)(orow + h) = v;
    }
}

// Correct-but-slow fallback if ws is too small for the packed weights.
__global__ __launch_bounds__(256) void tbcnn_fallback(
        const float* __restrict__ child, const float* __restrict__ parent,
        const float* __restrict__ Wl, const float* __restrict__ Wr,
        const float* __restrict__ Wt, const float* __restrict__ bias,
        float* __restrict__ out) {
    __shared__ float sl[XDIM], sr[XDIM], sp[XDIM];
    const int n = blockIdx.x;
    const int h = threadIdx.x;
    const float lwt[8] = {7.f/7.f, 6.f/7.f, 5.f/7.f, 4.f/7.f, 3.f/7.f, 2.f/7.f, 1.f/7.f, 0.f/7.f};
    const float rwt[8] = {0.f/7.f, 1.f/7.f, 2.f/7.f, 3.f/7.f, 4.f/7.f, 5.f/7.f, 6.f/7.f, 7.f/7.f};
    const float* ch = child + (size_t)n * (CDIM * XDIM);
    float al = 0.f, ar = 0.f;
#pragma unroll
    for (int c = 0; c < CDIM; ++c) {
        float v = ch[c * XDIM + h];
        al += lwt[c] * v;
        ar += rwt[c] * v;
    }
    sl[h] = al; sr[h] = ar; sp[h] = parent[(size_t)n * XDIM + h];
    __syncthreads();
    float a = bias[h];
    for (int x = 0; x < XDIM; ++x)
        a += sl[x] * Wl[(size_t)x * HDIM + h] + sr[x] * Wr[(size_t)x * HDIM + h]
           + sp[x] * Wt[(size_t)x * HDIM + h];
    out[(size_t)n * HDIM + h] = fmaxf(a, 0.f);
}

extern "C" void kernel_launch(void* const* d_in, const int* in_sizes, int n_in,
                              void* d_out, int out_size, void* d_ws, size_t ws_size,
                              hipStream_t stream) {
    const float* child  = (const float*)d_in[0];
    const float* parent = (const float*)d_in[1];
    const float* Wl     = (const float*)d_in[2];
    const float* Wr     = (const float*)d_in[3];
    const float* Wt     = (const float*)d_in[4];
    const float* bias   = (const float*)d_in[5];
    float* out = (float*)d_out;

    const size_t wp_bytes = (size_t)3 * XDIM * HDIM * sizeof(unsigned short); // 384 KiB
    if (ws_size >= wp_bytes) {
        bf16x8* wp = (bf16x8*)d_ws;
        pack_weights<<<96, 256, 0, stream>>>(Wl, Wr, Wt, wp);
        const int n_blocks = NROWS / 16;                 // 3125, exact
        tbcnn_main<<<n_blocks, 256, 0, stream>>>(child, parent, wp, bias, out);
    } else {
        tbcnn_fallback<<<NROWS, 256, 0, stream>>>(child, parent, Wl, Wr, Wt, bias, out);
    }
}